// Round 7
// baseline (4837.898 us; speedup 1.0000x reference)
//
#include <hip/hip_runtime.h>

typedef _Float16 half2_t __attribute__((ext_vector_type(2)));

#define NB 64
#define NT 2048
#define ND 256
#define NH 256
#define NTHR 1024
#define CHUNK 32
#define NCHUNK (NT / CHUNK)   // 64

// consumer LDS: hb/vb as [4 q-blocks][36] half2 (32 data + 4 pad -> conflict-free)
#define HV_STRIDE 36
// Total static LDS: 21504 half2 units = 86016 B > 80 KB.
// This makes 2 WGs/CU physically impossible, so the backend's occupancy
// estimate (computed from LDS size) drops to 1 WG = 4 waves/EU, raising the
// VGPR budget to 512/4 = 128 — enough for the 96 weight regs + working set.
#define LDS_UNITS 21504

__device__ __forceinline__ float sigmoid_f(float x) { return 1.f / (1.f + __expf(-x)); }
__device__ __forceinline__ float tanh_f(float x)    { return 1.f - 2.f / (1.f + __expf(2.f * x)); }
__device__ __forceinline__ half2_t mkh2(float a, float b) {
    half2_t r; r.x = (_Float16)a; r.y = (_Float16)b; return r;
}
__device__ __forceinline__ float h2get(unsigned u, int idx) {
    half2_t h = __builtin_bit_cast(half2_t, u);
    return idx ? (float)h.y : (float)h.x;
}
// identity asm: value becomes asm-defined -> cannot be rematerialized from memory.
__device__ __forceinline__ half2_t pin(half2_t x) {
    unsigned u = __builtin_bit_cast(unsigned, x);
    asm("" : "+v"(u));
    return __builtin_bit_cast(half2_t, u);
}
// barrier draining only LDS (lgkm), NOT vmcnt: global stores/loads stay in flight.
#define BAR_LDS() asm volatile("s_waitcnt lgkmcnt(0)\n\ts_barrier" ::: "memory")

// Grid 256 x 1024, all co-resident (1 WG/CU — enforced by the 84 KB LDS block).
//  bid <  64 : consumer — full GRU recurrence for batch=bid. 16 waves; 256 cols x
//              4 k-quarters; ALL THREE gate h-part weight slices in VGPRs
//              (3 x 32 half2 = 96 regs). LDS only for h/v broadcast.
//  bid >= 64 : producer (gate g, batch b) — x-projections into a ring in ws,
//              RELAXED agent atomics + vmcnt drain before flag store.
extern "C" __global__
__attribute__((amdgpu_flat_work_group_size(NTHR, NTHR)))
__attribute__((amdgpu_waves_per_eu(4, 4)))
void gru_fused(const float* __restrict__ x,
               const float* __restrict__ Wz, const float* __restrict__ bz,
               const float* __restrict__ Wr, const float* __restrict__ br,
               const float* __restrict__ Wh, const float* __restrict__ bh,
               float* __restrict__ out,
               unsigned* prodflag, unsigned* consflag,
               unsigned long long* preZR, unsigned* preH, int ring)
{
    __shared__ __align__(16) half2_t smem[LDS_UNITS];
    const int tid = threadIdx.x;
    const int bid = blockIdx.x;
    const int rmask = ring - 1;

    if (bid >= NB) {
        // ---------------- producer ----------------
        const int pb = bid - NB;        // 0..191
        const int g  = pb >> 6;         // 0=z 1=r 2=h
        const int b  = pb & 63;
        const float* W    = (g == 0) ? Wz : (g == 1) ? Wr : Wh;
        const float* bias = (g == 0) ? bz : (g == 1) ? br : bh;
        const int kh = tid & 1;         // k-half of 256 x-inputs
        const int c  = (tid >> 1) & 255;
        const int th = tid >> 9;        // 0..1 -> 16 steps each

        half2_t w2[64];                 // rows kh*128..+127 (x part), col c
        {
            const int kb = kh * 128;
            #pragma unroll
            for (int i = 0; i < 64; ++i)
                w2[i] = pin(mkh2(W[(kb + 2*i) * NH + c], W[(kb + 2*i + 1) * NH + c]));
        }
        const float bv = bias[c];
        half2_t* xl = smem;             // 32 steps * 128 half2

        for (int ch = 0; ch < NCHUNK; ++ch) {
            const int lead = ch * CHUNK + CHUNK - ring;
            if (lead > 0) {
                if (tid == 0) {
                    unsigned it = 0;
                    while ((int)__hip_atomic_load(&consflag[b], __ATOMIC_RELAXED,
                                                  __HIP_MEMORY_SCOPE_AGENT) < lead) {
                        __builtin_amdgcn_s_sleep(8);
                        if (++it > (1u << 20)) break;
                    }
                }
                __syncthreads();
            }
            const int t0 = ch * CHUNK;
            {
                const float4* xs = reinterpret_cast<const float4*>(
                    x + (size_t)b * NT * ND + (size_t)t0 * ND);
                #pragma unroll
                for (int rep = 0; rep < 2; ++rep) {
                    const int idx = rep * NTHR + tid;   // 0..2047 float4s
                    const float4 v = xs[idx];
                    xl[idx * 2]     = mkh2(v.x, v.y);
                    xl[idx * 2 + 1] = mkh2(v.z, v.w);
                }
            }
            __syncthreads();
            #pragma unroll 1
            for (int i = 0; i < 16; ++i) {
                const int tt = th * 16 + i;
                const half2_t* xr = &xl[tt * 128 + kh * 64];
                float a0 = 0.f, a1 = 0.f;
                #pragma unroll
                for (int k = 0; k < 32; ++k) {
                    a0 = __builtin_amdgcn_fdot2(xr[k],      w2[k],      a0, false);
                    a1 = __builtin_amdgcn_fdot2(xr[k + 32], w2[k + 32], a1, false);
                }
                float a = a0 + a1;
                a += __shfl_xor(a, 1, 64);   // combine k-halves
                a += bv;
                const float an = __shfl_xor(a, 2, 64);  // partner column c+1
                if (!(tid & 3)) {            // kh==0 && c even
                    const unsigned pk = __builtin_bit_cast(unsigned, mkh2(a, an));
                    const size_t slot = (size_t)b * ring + ((t0 + tt) & rmask);
                    if (g == 2) {
                        __hip_atomic_store(&preH[slot * 128 + (c >> 1)], pk,
                                           __ATOMIC_RELAXED, __HIP_MEMORY_SCOPE_AGENT);
                    } else {
                        unsigned* zr32 = reinterpret_cast<unsigned*>(&preZR[slot * 128 + (c >> 1)]);
                        __hip_atomic_store(&zr32[g], pk,
                                           __ATOMIC_RELAXED, __HIP_MEMORY_SCOPE_AGENT);
                    }
                }
            }
            asm volatile("s_waitcnt vmcnt(0)" ::: "memory");  // drain own stores
            __syncthreads();
            if (tid == 0)
                __hip_atomic_store(&prodflag[b * 3 + g], (unsigned)(ch + 1),
                                   __ATOMIC_RELAXED, __HIP_MEMORY_SCOPE_AGENT);
            __syncthreads();
        }
        return;
    }

    // ---------------- consumer: recurrence for batch b ----------------
    const int b   = bid;
    const int c   = tid >> 2;        // output column 0..255
    const int q   = tid & 3;         // k-quarter of the 256 h inputs
    const int sub = c & 1;           // half of the packed pre col-pair
    half2_t* hb = smem;              // [4][36]
    half2_t* vb = smem + 4 * HV_STRIDE;

    // register weights: all 3 gates, rows ND+q*64..+63, col c (32 half2 each)
    half2_t wzq[32], wrq[32], whq[32];
    {
        const int kb = ND + q * 64;
        #pragma unroll
        for (int i = 0; i < 32; ++i) {
            wzq[i] = pin(mkh2(Wz[(kb + 2*i) * NH + c], Wz[(kb + 2*i + 1) * NH + c]));
            wrq[i] = pin(mkh2(Wr[(kb + 2*i) * NH + c], Wr[(kb + 2*i + 1) * NH + c]));
            whq[i] = pin(mkh2(Wh[(kb + 2*i) * NH + c], Wh[(kb + 2*i + 1) * NH + c]));
        }
    }
    if (tid < 2 * 4 * HV_STRIDE) smem[tid] = mkh2(0.f, 0.f);  // zero hb+vb
    float hreg = 0.f;

    // wait for chunk 0 of all 3 gates
    if (tid < 3) {
        unsigned it = 0;
        while (__hip_atomic_load(&prodflag[b * 3 + tid], __ATOMIC_RELAXED,
                                 __HIP_MEMORY_SCOPE_AGENT) < 1u) {
            __builtin_amdgcn_s_sleep(8);
            if (++it > (1u << 20)) break;
        }
    }
    __syncthreads();

    const unsigned long long* zrbase = preZR + (size_t)b * ring * 128 + (c >> 1);
    const unsigned*           hhbase = preH  + (size_t)b * ring * 128 + (c >> 1);
    float* outb = out + (size_t)b * NT * NH + c;

    for (int t = 0; t < NT; ++t) {
        if (t && !(t & (CHUNK - 1))) {   // chunk boundary: publish + poll
            if (tid == 0)
                __hip_atomic_store(&consflag[b], (unsigned)t,
                                   __ATOMIC_RELAXED, __HIP_MEMORY_SCOPE_AGENT);
            const unsigned need = (unsigned)((t >> 5) + 1);
            if (tid < 3) {
                unsigned it = 0;
                while (__hip_atomic_load(&prodflag[b * 3 + tid], __ATOMIC_RELAXED,
                                         __HIP_MEMORY_SCOPE_AGENT) < need) {
                    __builtin_amdgcn_s_sleep(8);
                    if (++it > (1u << 20)) break;
                }
            }
            __syncthreads();
        }
        // this step's pre-activations: issued now, z/r used after stage-A dots,
        // h used after stage-B dots (~500+ cycles of latency hiding)
        const int so = (t & rmask) * 128;
        const unsigned long long zr = __hip_atomic_load(zrbase + so,
                                          __ATOMIC_RELAXED, __HIP_MEMORY_SCOPE_AGENT);
        const unsigned hh = __hip_atomic_load(hhbase + so,
                                          __ATOMIC_RELAXED, __HIP_MEMORY_SCOPE_AGENT);

        // ---- stage A: z, r over this thread's 64 h-inputs ----
        const half2_t* hsrc = hb + q * HV_STRIDE;
        float az = 0.f, ar = 0.f;
        #pragma unroll
        for (int i = 0; i < 32; ++i) {
            const half2_t hv = hsrc[i];
            az = __builtin_amdgcn_fdot2(hv, wzq[i], az, false);
            ar = __builtin_amdgcn_fdot2(hv, wrq[i], ar, false);
        }
        az += __shfl_xor(az, 1, 64); az += __shfl_xor(az, 2, 64);
        ar += __shfl_xor(ar, 1, 64); ar += __shfl_xor(ar, 2, 64);
        const float z = sigmoid_f(az + h2get((unsigned)(zr & 0xffffffffu), sub));
        const float r = sigmoid_f(ar + h2get((unsigned)(zr >> 32), sub));
        const float v  = r * hreg;
        const float v1 = __shfl_xor(v, 4, 64);   // partner column c^1
        if (!(tid & 7)) vb[(c >> 6) * HV_STRIDE + ((c & 63) >> 1)] = mkh2(v, v1);
        BAR_LDS();   // vb ready

        // ---- stage B: h_hat over v, then h_new ----
        const half2_t* vsrc = vb + q * HV_STRIDE;
        float ah = 0.f;
        #pragma unroll
        for (int i = 0; i < 32; ++i)
            ah = __builtin_amdgcn_fdot2(vsrc[i], whq[i], ah, false);
        ah += __shfl_xor(ah, 1, 64); ah += __shfl_xor(ah, 2, 64);
        const float hhat = tanh_f(ah + h2get(hh, sub));
        const float hn = hreg + z * (hhat - hreg);
        hreg = hn;
        if (q == 0) outb[(size_t)t * NH] = hn;
        const float hn1 = __shfl_xor(hn, 4, 64);
        if (!(tid & 7)) hb[(c >> 6) * HV_STRIDE + ((c & 63) >> 1)] = mkh2(hn, hn1);
        BAR_LDS();   // hb = h_t everywhere
    }
}

extern "C" void kernel_launch(void* const* d_in, const int* in_sizes, int n_in,
                              void* d_out, int out_size, void* d_ws, size_t ws_size,
                              hipStream_t stream) {
    const float* x  = (const float*)d_in[0];
    const float* Wz = (const float*)d_in[1];
    const float* bz = (const float*)d_in[2];
    const float* Wr = (const float*)d_in[3];
    const float* br = (const float*)d_in[4];
    const float* Wh = (const float*)d_in[5];
    const float* bh = (const float*)d_in[6];
    float* outp = (float*)d_out;

    // ring sizing: per ring-step bytes = NB*128*12 = 96 KiB
    const size_t base = 4096;
    int ring = 32;
    for (int r = 2048; r >= 32; r >>= 1) {
        const size_t need = base + (size_t)NB * r * 128 * 12;
        if (need <= ws_size) { ring = r; break; }
    }
    char* w = (char*)d_ws;
    unsigned* prodflag = (unsigned*)w;                 // [64][3]
    unsigned* consflag = (unsigned*)(w + 1024);        // [64]
    unsigned long long* preZR = (unsigned long long*)(w + base);          // [64][ring][128]
    unsigned* preH = (unsigned*)(w + base + (size_t)NB * ring * 128 * 8); // [64][ring][128]

    hipMemsetAsync(w, 0, 4096, stream);  // flags must start at 0 each launch
    gru_fused<<<256, NTHR, 0, stream>>>(x, Wz, bz, Wr, br, Wh, bh, outp,
                                        prodflag, consflag, preZR, preH, ring);
}

// Round 8
// 4678.796 us; speedup vs baseline: 1.0340x; 1.0340x over previous
//
#include <hip/hip_runtime.h>

typedef _Float16 half2_t __attribute__((ext_vector_type(2)));

#define NB 64
#define NT 2048
#define ND 256
#define NH 256
#define NTHR 1024
#define CHUNK 32
#define NCHUNK (NT / CHUNK)   // 64

// ---- consumer LDS map (dword units) ----
// wzr: int8 z,r h-part weights, [c][q*33 + i*2 + g], col stride 131 (odd -> <=2-way banks)
#define WQ_C 131
#define WQ_Q 33
#define HQ_OFF (256 * WQ_C)          // h_q int8[256] = 64 dw (+8 pad)
#define VB_OFF (HQ_OFF + 72)         // vb fp16: [4][36] dw, conflict-free
#define VB_STRIDE 36
#define LDS_DW (VB_OFF + 4 * VB_STRIDE + 8)
// ---- producer LDS map: x-stage [32 t][148], block kq*36 (b128-aligned, conflict-free)
#define XT_STRIDE 148

__device__ __forceinline__ float sigmoid_f(float x) { return 1.f / (1.f + __expf(-x)); }
__device__ __forceinline__ float tanh_f(float x)    { return 1.f - 2.f / (1.f + __expf(2.f * x)); }
__device__ __forceinline__ half2_t mkh2(float a, float b) {
    half2_t r; r.x = (_Float16)a; r.y = (_Float16)b; return r;
}
__device__ __forceinline__ half2_t u2h2(unsigned u) { return __builtin_bit_cast(half2_t, u); }
__device__ __forceinline__ float h2get(unsigned u, int idx) {
    half2_t h = u2h2(u);
    return idx ? (float)h.y : (float)h.x;
}
__device__ __forceinline__ int dot4i8(int a, int b, int c) {
#if __has_builtin(__builtin_amdgcn_sdot4)
    return __builtin_amdgcn_sdot4(a, b, c, false);
#else
    int s = c;
    #pragma unroll
    for (int j = 0; j < 4; ++j)
        s += ((a << (24 - 8 * j)) >> 24) * ((b << (24 - 8 * j)) >> 24);
    return s;
#endif
}
// barrier draining only LDS (lgkm); global loads/stores stay in flight.
#define BAR_LDS() asm volatile("s_waitcnt lgkmcnt(0)\n\ts_barrier" ::: "memory")

// dequant: w ~ q_w/508 (round(w*508), |w|<0.25), h ~ q_h/127
#define DEQ (1.0f / 64516.0f)

// Grid 256 x 1024, all co-resident (1 WG/CU, big LDS).
//  bid <  64 : consumer — recurrence for batch=bid. 256 cols x 4 k-quarters.
//              h-gate fp16 weights in regs (32 half2); z,r gates int8 in LDS;
//              h_prev int8-quantized in LDS (scale 127; |h|<=1 by convexity).
//  bid >= 64 : producer (gate g, batch b) — x-projections into ring in ws.
//              4-way-k lane split => 32 half2 weights/thread, fits 64-reg budget.
extern "C" __global__ void __launch_bounds__(NTHR)
gru_fused(const float* __restrict__ x,
          const float* __restrict__ Wz, const float* __restrict__ bz,
          const float* __restrict__ Wr, const float* __restrict__ br,
          const float* __restrict__ Wh, const float* __restrict__ bh,
          float* __restrict__ out,
          unsigned* prodflag, unsigned* consflag,
          unsigned long long* preZR, unsigned* preH, int ring)
{
    __shared__ __align__(16) unsigned smem[LDS_DW];
    const int tid = threadIdx.x;
    const int bid = blockIdx.x;
    const int rmask = ring - 1;

    if (bid >= NB) {
        // ---------------- producer ----------------
        const int pb = bid - NB;        // 0..191
        const int g  = pb >> 6;         // 0=z 1=r 2=h
        const int b  = pb & 63;
        const float* W    = (g == 0) ? Wz : (g == 1) ? Wr : Wh;
        const float* bias = (g == 0) ? bz : (g == 1) ? br : bh;
        const int c  = tid >> 2;        // col 0..255
        const int kq = tid & 3;         // k-quarter of 256 x-inputs

        half2_t w2[32];                 // x-part rows kq*64..+63, col c
        #pragma unroll
        for (int j = 0; j < 32; ++j)
            w2[j] = mkh2(W[(kq * 64 + 2 * j) * NH + c], W[(kq * 64 + 2 * j + 1) * NH + c]);
        const float bv = bias[c];

        for (int ch = 0; ch < NCHUNK; ++ch) {
            const int lead = ch * CHUNK + CHUNK - ring;
            if (lead > 0) {
                if (tid == 0) {
                    unsigned it = 0;
                    while ((int)__hip_atomic_load(&consflag[b], __ATOMIC_RELAXED,
                                                  __HIP_MEMORY_SCOPE_AGENT) < lead) {
                        __builtin_amdgcn_s_sleep(8);
                        if (++it > (1u << 20)) break;
                    }
                }
                __syncthreads();
            }
            const int t0 = ch * CHUNK;
            {   // stage x[b][t0..t0+31][:] -> [t][kq-block][36] half2 layout
                const float4* xs = reinterpret_cast<const float4*>(
                    x + (size_t)b * NT * ND + (size_t)t0 * ND);
                #pragma unroll
                for (int rep = 0; rep < 2; ++rep) {
                    const int f = rep * NTHR + tid;     // 0..2047 float4s
                    const float4 v = xs[f];
                    const int t  = f >> 6;
                    const int u2 = f & 63;
                    const unsigned dst = t * XT_STRIDE + (u2 >> 4) * 36 + ((2 * u2) & 31);
                    smem[dst]     = __builtin_bit_cast(unsigned, mkh2(v.x, v.y));
                    smem[dst + 1] = __builtin_bit_cast(unsigned, mkh2(v.z, v.w));
                }
            }
            __syncthreads();
            #pragma unroll 1
            for (int t = 0; t < CHUNK; ++t) {
                const uint4* xr4 = reinterpret_cast<const uint4*>(
                    &smem[t * XT_STRIDE + kq * 36]);
                float a0 = 0.f, a1 = 0.f;
                #pragma unroll
                for (int blk = 0; blk < 8; ++blk) {
                    const uint4 xv = xr4[blk];
                    a0 = __builtin_amdgcn_fdot2(u2h2(xv.x), w2[blk*4+0], a0, false);
                    a1 = __builtin_amdgcn_fdot2(u2h2(xv.y), w2[blk*4+1], a1, false);
                    a0 = __builtin_amdgcn_fdot2(u2h2(xv.z), w2[blk*4+2], a0, false);
                    a1 = __builtin_amdgcn_fdot2(u2h2(xv.w), w2[blk*4+3], a1, false);
                }
                float a = a0 + a1;
                a += __shfl_xor(a, 1, 64);
                a += __shfl_xor(a, 2, 64);   // kq-reduce
                a += bv;
                const float an = __shfl_xor(a, 4, 64);  // partner col c^1
                if (!(tid & 7)) {            // kq==0 && c even
                    const unsigned pk = __builtin_bit_cast(unsigned, mkh2(a, an));
                    const size_t slot = (size_t)b * ring + ((t0 + t) & rmask);
                    if (g == 2) {
                        __hip_atomic_store(&preH[slot * 128 + (c >> 1)], pk,
                                           __ATOMIC_RELAXED, __HIP_MEMORY_SCOPE_AGENT);
                    } else {
                        unsigned* zr32 = reinterpret_cast<unsigned*>(&preZR[slot * 128 + (c >> 1)]);
                        __hip_atomic_store(&zr32[g], pk,
                                           __ATOMIC_RELAXED, __HIP_MEMORY_SCOPE_AGENT);
                    }
                }
            }
            asm volatile("s_waitcnt vmcnt(0)" ::: "memory");  // drain ring stores
            __syncthreads();
            if (tid == 0)
                __hip_atomic_store(&prodflag[b * 3 + g], (unsigned)(ch + 1),
                                   __ATOMIC_RELAXED, __HIP_MEMORY_SCOPE_AGENT);
            __syncthreads();
        }
        return;
    }

    // ---------------- consumer: recurrence for batch b ----------------
    const int b   = bid;
    const int c   = tid >> 2;        // output column 0..255
    const int q   = tid & 3;         // k-quarter of the 256 h inputs
    const int sub = c & 1;           // half of the packed pre col-pair

    // build int8 z,r weight tables in LDS: thread (cc, p) fills q=p slice of col cc
    {
        const int cc = tid & 255;
        const int p  = tid >> 8;     // 0..3
        #pragma unroll 1
        for (int g = 0; g < 2; ++g) {
            const float* W = g ? Wr : Wz;
            #pragma unroll 1
            for (int i = 0; i < 16; ++i) {
                const int k = ND + p * 64 + i * 4;
                unsigned d = 0;
                #pragma unroll
                for (int j = 0; j < 4; ++j) {
                    const float w = W[(k + j) * NH + cc];
                    int qv = __float2int_rn(w * 508.0f);
                    qv = qv > 127 ? 127 : (qv < -127 ? -127 : qv);
                    d |= ((unsigned)(qv & 255)) << (8 * j);
                }
                smem[cc * WQ_C + p * WQ_Q + i * 2 + g] = d;
            }
        }
    }
    // h-gate fp16 weights in regs: rows ND+q*64..+63, col c (32 half2)
    half2_t whq[32];
    #pragma unroll
    for (int j = 0; j < 32; ++j)
        whq[j] = mkh2(Wh[(ND + q * 64 + 2 * j) * NH + c],
                      Wh[(ND + q * 64 + 2 * j + 1) * NH + c]);
    // zero h_q (h0=0 -> bytes 0) and vb
    if (tid < LDS_DW - HQ_OFF) smem[HQ_OFF + tid] = 0u;
    float hreg = 0.f;

    // wait for chunk 0 of all 3 gates
    if (tid < 3) {
        unsigned it = 0;
        while (__hip_atomic_load(&prodflag[b * 3 + tid], __ATOMIC_RELAXED,
                                 __HIP_MEMORY_SCOPE_AGENT) < 1u) {
            __builtin_amdgcn_s_sleep(8);
            if (++it > (1u << 20)) break;
        }
    }
    __syncthreads();

    const unsigned long long* zrbase = preZR + (size_t)b * ring * 128 + (c >> 1);
    const unsigned*           hhbase = preH  + (size_t)b * ring * 128 + (c >> 1);
    float* outb = out + (size_t)b * NT * NH + c;
    const unsigned* wp  = smem + c * WQ_C + q * WQ_Q;       // z,r int8 weights
    const uint4*    hq4 = reinterpret_cast<const uint4*>(smem + HQ_OFF) + q * 4;
    const uint4*    vb4 = reinterpret_cast<const uint4*>(smem + VB_OFF + q * VB_STRIDE);

    #pragma unroll 1
    for (int t = 0; t < NT; ++t) {
        if (t && !(t & (CHUNK - 1))) {   // chunk boundary: publish + poll
            if (tid == 0)
                __hip_atomic_store(&consflag[b], (unsigned)t,
                                   __ATOMIC_RELAXED, __HIP_MEMORY_SCOPE_AGENT);
            const unsigned need = (unsigned)((t >> 5) + 1);
            if (tid < 3) {
                unsigned it = 0;
                while (__hip_atomic_load(&prodflag[b * 3 + tid], __ATOMIC_RELAXED,
                                         __HIP_MEMORY_SCOPE_AGENT) < need) {
                    __builtin_amdgcn_s_sleep(8);
                    if (++it > (1u << 20)) break;
                }
            }
            __syncthreads();
        }
        // this step's pre-activations (global, latency hidden under the dots)
        const int so = (t & rmask) * 128;
        const unsigned long long zr = __hip_atomic_load(zrbase + so,
                                          __ATOMIC_RELAXED, __HIP_MEMORY_SCOPE_AGENT);
        const unsigned hh = __hip_atomic_load(hhbase + so,
                                          __ATOMIC_RELAXED, __HIP_MEMORY_SCOPE_AGENT);

        // ---- stage A: z, r int8 dots over this thread's 64 h-inputs ----
        int az = 0, ar = 0;
        #pragma unroll
        for (int blk = 0; blk < 4; ++blk) {
            const uint4 hb = hq4[blk];
            az = dot4i8((int)hb.x, (int)wp[(blk*4+0)*2+0], az);
            ar = dot4i8((int)hb.x, (int)wp[(blk*4+0)*2+1], ar);
            az = dot4i8((int)hb.y, (int)wp[(blk*4+1)*2+0], az);
            ar = dot4i8((int)hb.y, (int)wp[(blk*4+1)*2+1], ar);
            az = dot4i8((int)hb.z, (int)wp[(blk*4+2)*2+0], az);
            ar = dot4i8((int)hb.z, (int)wp[(blk*4+2)*2+1], ar);
            az = dot4i8((int)hb.w, (int)wp[(blk*4+3)*2+0], az);
            ar = dot4i8((int)hb.w, (int)wp[(blk*4+3)*2+1], ar);
        }
        az += __shfl_xor(az, 1, 64); az += __shfl_xor(az, 2, 64);
        ar += __shfl_xor(ar, 1, 64); ar += __shfl_xor(ar, 2, 64);
        const float z = sigmoid_f((float)az * DEQ + h2get((unsigned)(zr & 0xffffffffu), sub));
        const float r = sigmoid_f((float)ar * DEQ + h2get((unsigned)(zr >> 32), sub));
        const float v  = r * hreg;                      // exact fp32 h
        const float v1 = __shfl_xor(v, 4, 64);          // partner col c^1
        if (!(tid & 7))
            smem[VB_OFF + (c >> 6) * VB_STRIDE + ((c & 63) >> 1)] =
                __builtin_bit_cast(unsigned, mkh2(v, v1));
        BAR_LDS();   // vb ready

        // ---- stage B: h_hat fp16 dots (weights in regs), then h_new ----
        float ah0 = 0.f, ah1 = 0.f;
        #pragma unroll
        for (int blk = 0; blk < 8; ++blk) {
            const uint4 vv = vb4[blk];
            ah0 = __builtin_amdgcn_fdot2(u2h2(vv.x), whq[blk*4+0], ah0, false);
            ah1 = __builtin_amdgcn_fdot2(u2h2(vv.y), whq[blk*4+1], ah1, false);
            ah0 = __builtin_amdgcn_fdot2(u2h2(vv.z), whq[blk*4+2], ah0, false);
            ah1 = __builtin_amdgcn_fdot2(u2h2(vv.w), whq[blk*4+3], ah1, false);
        }
        float ah = ah0 + ah1;
        ah += __shfl_xor(ah, 1, 64); ah += __shfl_xor(ah, 2, 64);
        const float hhat = tanh_f(ah + h2get(hh, sub));
        const float hn = hreg + z * (hhat - hreg);      // |hn| <= 1
        hreg = hn;
        if (q == 0) outb[(size_t)t * NH] = hn;
        // quantize h_new to int8 and pack 4 cols/dword
        {
            const int qi = __float2int_rn(hn * 127.0f) & 255;
            const int o4 = __shfl_xor(qi, 4, 64);
            const int lo = (tid & 4) ? o4 : qi, hi = (tid & 4) ? qi : o4;
            const int p2 = lo | (hi << 8);
            const int o8 = __shfl_xor(p2, 8, 64);
            const int lo2 = (tid & 8) ? o8 : p2, hi2 = (tid & 8) ? p2 : o8;
            if (!(tid & 15))
                smem[HQ_OFF + (c >> 2)] =
                    ((unsigned)lo2 & 0xffffu) | ((unsigned)hi2 << 16);
        }
        BAR_LDS();   // h_q = h_t everywhere
    }
}

extern "C" void kernel_launch(void* const* d_in, const int* in_sizes, int n_in,
                              void* d_out, int out_size, void* d_ws, size_t ws_size,
                              hipStream_t stream) {
    const float* x  = (const float*)d_in[0];
    const float* Wz = (const float*)d_in[1];
    const float* bz = (const float*)d_in[2];
    const float* Wr = (const float*)d_in[3];
    const float* br = (const float*)d_in[4];
    const float* Wh = (const float*)d_in[5];
    const float* bh = (const float*)d_in[6];
    float* outp = (float*)d_out;

    // ring sizing: per ring-step bytes = NB*128*12 = 96 KiB
    const size_t base = 4096;
    int ring = 32;
    for (int r = 2048; r >= 32; r >>= 1) {
        const size_t need = base + (size_t)NB * r * 128 * 12;
        if (need <= ws_size) { ring = r; break; }
    }
    char* w = (char*)d_ws;
    unsigned* prodflag = (unsigned*)w;                 // [64][3]
    unsigned* consflag = (unsigned*)(w + 1024);        // [64]
    unsigned long long* preZR = (unsigned long long*)(w + base);          // [64][ring][128]
    unsigned* preH = (unsigned*)(w + base + (size_t)NB * ring * 128 * 8); // [64][ring][128]

    hipMemsetAsync(w, 0, 4096, stream);  // flags must start at 0 each launch
    gru_fused<<<256, NTHR, 0, stream>>>(x, Wz, bz, Wr, br, Wh, bh, outp,
                                        prodflag, consflag, preZR, preH, ring);
}

// Round 9
// 2214.211 us; speedup vs baseline: 2.1849x; 2.1131x over previous
//
#include <hip/hip_runtime.h>

typedef _Float16 half2_t __attribute__((ext_vector_type(2)));

#define NB 64
#define NT 2048
#define ND 256
#define NH 256
#define NTHR 512
#define CHUNK 32
#define NCHUNK (NT / CHUNK)   // 64

// LDS (dword units). Producer: x-stage [32 t][132]. Consumer: hq bytes[256] at
// dw 0..63, vq bytes[256] at dw 64..127 (b128 broadcast reads, conflict-free).
#define XT_STRIDE 132
#define LDS_DW (32 * XT_STRIDE + 16)
#define VQ_BYTE 256

__device__ __forceinline__ float sigmoid_f(float x) { return 1.f / (1.f + __expf(-x)); }
__device__ __forceinline__ float tanh_f(float x)    { return 1.f - 2.f / (1.f + __expf(2.f * x)); }
__device__ __forceinline__ half2_t mkh2(float a, float b) {
    half2_t r; r.x = (_Float16)a; r.y = (_Float16)b; return r;
}
__device__ __forceinline__ half2_t u2h2(unsigned u) { return __builtin_bit_cast(half2_t, u); }
__device__ __forceinline__ float h2get(unsigned u, int idx) {
    half2_t h = u2h2(u);
    return idx ? (float)h.y : (float)h.x;
}
// int8x4 dot: builtin if present, else the raw instruction (never the 8-op C fallback)
__device__ __forceinline__ int dot4i8(unsigned a, unsigned b, int c) {
#if __has_builtin(__builtin_amdgcn_sdot4)
    return __builtin_amdgcn_sdot4((int)a, (int)b, c, false);
#else
    int d;
    asm("v_dot4_i32_i8 %0, %1, %2, %3" : "=v"(d) : "v"(a), "v"(b), "v"(c));
    return d;
#endif
}
// barrier draining only LDS (lgkm); global loads/stores stay in flight.
#define BAR_LDS() asm volatile("s_waitcnt lgkmcnt(0)\n\ts_barrier" ::: "memory")

// Grid 256 x 512 (>= co-residency guaranteed: capacity 2 WG/CU).
//  bid <  64 : consumer — recurrence for batch=bid. 256 cols x 2 k-halves.
//              ALL 3 gate h-part weight slices int8 in VGPRs (96 dw/thread,
//              per-thread max-scale). LDS holds only int8 h/v (256 B each).
//  bid >= 64 : producer (gate g, batch b) — x-projections into ring in ws,
//              RELAXED agent atomics + vmcnt drain before flag store.
extern "C" __global__ void __launch_bounds__(NTHR)
gru_fused(const float* __restrict__ x,
          const float* __restrict__ Wz, const float* __restrict__ bz,
          const float* __restrict__ Wr, const float* __restrict__ br,
          const float* __restrict__ Wh, const float* __restrict__ bh,
          float* __restrict__ out,
          unsigned* prodflag, unsigned* consflag,
          unsigned long long* preZR, unsigned* preH, int ring)
{
    __shared__ __align__(16) unsigned smem[LDS_DW];
    const int tid = threadIdx.x;
    const int bid = blockIdx.x;
    const int rmask = ring - 1;
    const int c  = tid >> 1;       // column 0..255
    const int kh = tid & 1;        // k-half (128 inputs each)

    if (bid >= NB) {
        // ---------------- producer ----------------
        const int pb = bid - NB;        // 0..191
        const int g  = pb >> 6;         // 0=z 1=r 2=h
        const int b  = pb & 63;
        const float* W    = (g == 0) ? Wz : (g == 1) ? Wr : Wh;
        const float* bias = (g == 0) ? bz : (g == 1) ? br : bh;

        half2_t w2[64];                 // x-part rows kh*128..+127, col c
        #pragma unroll
        for (int j = 0; j < 64; ++j)
            w2[j] = mkh2(W[(kh * 128 + 2 * j) * NH + c],
                         W[(kh * 128 + 2 * j + 1) * NH + c]);
        const float bv = bias[c];

        for (int ch = 0; ch < NCHUNK; ++ch) {
            const int lead = ch * CHUNK + CHUNK - ring;
            if (lead > 0) {
                if (tid == 0) {
                    unsigned it = 0;
                    while ((int)__hip_atomic_load(&consflag[b], __ATOMIC_RELAXED,
                                                  __HIP_MEMORY_SCOPE_AGENT) < lead) {
                        __builtin_amdgcn_s_sleep(8);
                        if (++it > (1u << 20)) break;
                    }
                }
                __syncthreads();
            }
            const int t0 = ch * CHUNK;
            {   // stage x[b][t0..t0+31][:] into LDS as half2, row stride 132 dw
                const float4* xs = reinterpret_cast<const float4*>(
                    x + (size_t)b * NT * ND + (size_t)t0 * ND);
                #pragma unroll
                for (int rep = 0; rep < 4; ++rep) {
                    const int f = rep * NTHR + tid;     // 0..2047 float4s
                    const float4 v = xs[f];
                    const int tt = f >> 6;
                    const int u2 = f & 63;
                    uint2 pk;
                    pk.x = __builtin_bit_cast(unsigned, mkh2(v.x, v.y));
                    pk.y = __builtin_bit_cast(unsigned, mkh2(v.z, v.w));
                    *reinterpret_cast<uint2*>(&smem[tt * XT_STRIDE + u2 * 2]) = pk;
                }
            }
            __syncthreads();
            #pragma unroll 1
            for (int t = 0; t < CHUNK; ++t) {
                const uint4* xr4 = reinterpret_cast<const uint4*>(
                    &smem[t * XT_STRIDE + kh * 64]);
                float a0 = 0.f, a1 = 0.f, a2 = 0.f, a3 = 0.f;
                #pragma unroll
                for (int i = 0; i < 16; ++i) {
                    const uint4 xv = xr4[i];
                    a0 = __builtin_amdgcn_fdot2(u2h2(xv.x), w2[i*4+0], a0, false);
                    a1 = __builtin_amdgcn_fdot2(u2h2(xv.y), w2[i*4+1], a1, false);
                    a2 = __builtin_amdgcn_fdot2(u2h2(xv.z), w2[i*4+2], a2, false);
                    a3 = __builtin_amdgcn_fdot2(u2h2(xv.w), w2[i*4+3], a3, false);
                }
                float a = (a0 + a1) + (a2 + a3);
                a += __shfl_xor(a, 1, 64);   // combine k-halves
                a += bv;
                const float an = __shfl_xor(a, 2, 64);  // partner col c^1
                if (!(tid & 3)) {            // kh==0 && c even
                    const unsigned pk = __builtin_bit_cast(unsigned, mkh2(a, an));
                    const size_t slot = (size_t)b * ring + ((t0 + t) & rmask);
                    if (g == 2) {
                        __hip_atomic_store(&preH[slot * 128 + (c >> 1)], pk,
                                           __ATOMIC_RELAXED, __HIP_MEMORY_SCOPE_AGENT);
                    } else {
                        unsigned* zr32 = reinterpret_cast<unsigned*>(&preZR[slot * 128 + (c >> 1)]);
                        __hip_atomic_store(&zr32[g], pk,
                                           __ATOMIC_RELAXED, __HIP_MEMORY_SCOPE_AGENT);
                    }
                }
            }
            asm volatile("s_waitcnt vmcnt(0)" ::: "memory");  // drain ring stores
            __syncthreads();
            if (tid == 0)
                __hip_atomic_store(&prodflag[b * 3 + g], (unsigned)(ch + 1),
                                   __ATOMIC_RELAXED, __HIP_MEMORY_SCOPE_AGENT);
            __syncthreads();
        }
        return;
    }

    // ---------------- consumer: recurrence for batch b ----------------
    const int b   = bid;
    const int sub = c & 1;           // half of the packed pre col-pair
    const int kb  = ND + kh * 128;   // this thread's h-part row base

    // pass 1: per-thread per-gate max |w| -> quant scales
    float mxz = 1e-8f, mxr = 1e-8f, mxh = 1e-8f;
    #pragma unroll
    for (int j = 0; j < 128; ++j) {
        mxz = fmaxf(mxz, fabsf(Wz[(kb + j) * NH + c]));
        mxr = fmaxf(mxr, fabsf(Wr[(kb + j) * NH + c]));
        mxh = fmaxf(mxh, fabsf(Wh[(kb + j) * NH + c]));
    }
    const float qsz = 127.0f / mxz, qsr = 127.0f / mxr, qsh = 127.0f / mxh;
    const float deqz = mxz / (127.0f * 127.0f);
    const float deqr = mxr / (127.0f * 127.0f);
    const float deqh = mxh / (127.0f * 127.0f);

    // pass 2: quantize + pack into 8 uint4 per gate (96 VGPRs total)
    uint4 wz4[8], wr4[8], wh4[8];
    #pragma unroll
    for (int i = 0; i < 8; ++i) {
        unsigned dz[4], dr[4], dh[4];
        #pragma unroll
        for (int d = 0; d < 4; ++d) {
            unsigned az = 0, ar = 0, ah = 0;
            #pragma unroll
            for (int j = 0; j < 4; ++j) {
                const int k = (i * 4 + d) * 4 + j;
                const int qz = __float2int_rn(Wz[(kb + k) * NH + c] * qsz);
                const int qr = __float2int_rn(Wr[(kb + k) * NH + c] * qsr);
                const int qh = __float2int_rn(Wh[(kb + k) * NH + c] * qsh);
                az |= ((unsigned)(qz & 255)) << (8 * j);
                ar |= ((unsigned)(qr & 255)) << (8 * j);
                ah |= ((unsigned)(qh & 255)) << (8 * j);
            }
            dz[d] = az; dr[d] = ar; dh[d] = ah;
        }
        wz4[i] = make_uint4(dz[0], dz[1], dz[2], dz[3]);
        wr4[i] = make_uint4(dr[0], dr[1], dr[2], dr[3]);
        wh4[i] = make_uint4(dh[0], dh[1], dh[2], dh[3]);
    }

    if (tid < 128) smem[tid] = 0u;   // zero hq + vq (h0 = 0)
    float hreg = 0.f;

    // wait for chunk 0 of all 3 gates
    if (tid < 3) {
        unsigned it = 0;
        while (__hip_atomic_load(&prodflag[b * 3 + tid], __ATOMIC_RELAXED,
                                 __HIP_MEMORY_SCOPE_AGENT) < 1u) {
            __builtin_amdgcn_s_sleep(8);
            if (++it > (1u << 20)) break;
        }
    }
    __syncthreads();

    const unsigned long long* zrb = preZR + (size_t)b * ring * 128 + (c >> 1);
    const unsigned*           hhb = preH  + (size_t)b * ring * 128 + (c >> 1);
    float* outb = out + (size_t)b * NT * NH + c;
    const uint4* hq4 = reinterpret_cast<const uint4*>(smem) + kh * 8;
    const uint4* vq4 = reinterpret_cast<const uint4*>(
                           reinterpret_cast<const char*>(smem) + VQ_BYTE) + kh * 8;
    char* hqb = reinterpret_cast<char*>(smem);

    unsigned long long zr_c = __hip_atomic_load(zrb, __ATOMIC_RELAXED, __HIP_MEMORY_SCOPE_AGENT);
    unsigned           hh_c = __hip_atomic_load(hhb, __ATOMIC_RELAXED, __HIP_MEMORY_SCOPE_AGENT);

    #pragma unroll 1
    for (int t = 0; t < NT; ++t) {
        const int tn = t + 1;
        const bool pf = (tn < NT) && ((tn & (CHUNK - 1)) != 0);
        unsigned long long zr_n = 0; unsigned hh_n = 0;
        if (pf) {   // prefetch next step's pre-activations (latency hides under dots)
            const int so = (tn & rmask) * 128;
            zr_n = __hip_atomic_load(zrb + so, __ATOMIC_RELAXED, __HIP_MEMORY_SCOPE_AGENT);
            hh_n = __hip_atomic_load(hhb + so, __ATOMIC_RELAXED, __HIP_MEMORY_SCOPE_AGENT);
        }

        // ---- stage A: z, r int8 dots over this thread's 128 h-inputs ----
        int az0 = 0, az1 = 0, ar0 = 0, ar1 = 0;
        #pragma unroll
        for (int i = 0; i < 8; ++i) {
            const uint4 hv = hq4[i];
            const uint4 wz = wz4[i], wr = wr4[i];
            az0 = dot4i8(hv.x, wz.x, az0); az1 = dot4i8(hv.y, wz.y, az1);
            az0 = dot4i8(hv.z, wz.z, az0); az1 = dot4i8(hv.w, wz.w, az1);
            ar0 = dot4i8(hv.x, wr.x, ar0); ar1 = dot4i8(hv.y, wr.y, ar1);
            ar0 = dot4i8(hv.z, wr.z, ar0); ar1 = dot4i8(hv.w, wr.w, ar1);
        }
        float azf = (float)(az0 + az1) * deqz;
        float arf = (float)(ar0 + ar1) * deqr;
        azf += __shfl_xor(azf, 1, 64);
        arf += __shfl_xor(arf, 1, 64);
        const float z = sigmoid_f(azf + h2get((unsigned)(zr_c & 0xffffffffu), sub));
        const float r = sigmoid_f(arf + h2get((unsigned)(zr_c >> 32), sub));
        const float v = r * hreg;
        if (kh == 0)   // publish v[c] as int8 (|v| <= 1)
            hqb[VQ_BYTE + c] = (char)__float2int_rn(v * 127.0f);
        BAR_LDS();   // vq ready

        // ---- stage B: h_hat int8 dot over v, then h_new ----
        int ah0 = 0, ah1 = 0;
        #pragma unroll
        for (int i = 0; i < 8; ++i) {
            const uint4 vv = vq4[i];
            const uint4 wh = wh4[i];
            ah0 = dot4i8(vv.x, wh.x, ah0); ah1 = dot4i8(vv.y, wh.y, ah1);
            ah0 = dot4i8(vv.z, wh.z, ah0); ah1 = dot4i8(vv.w, wh.w, ah1);
        }
        float ahf = (float)(ah0 + ah1) * deqh;
        ahf += __shfl_xor(ahf, 1, 64);
        const float hhat = tanh_f(ahf + h2get(hh_c, sub));
        const float hn = hreg + z * (hhat - hreg);   // |hn| <= 1
        hreg = hn;
        if (kh == 0) {
            outb[(size_t)t * NH] = hn;
            hqb[c] = (char)__float2int_rn(hn * 127.0f);
        }
        BAR_LDS();   // hq = h_t everywhere

        if (pf) {
            zr_c = zr_n; hh_c = hh_n;
        } else if (tn < NT) {        // chunk boundary: publish + poll + reload
            if (tid == 0)
                __hip_atomic_store(&consflag[b], (unsigned)tn,
                                   __ATOMIC_RELAXED, __HIP_MEMORY_SCOPE_AGENT);
            const unsigned need = (unsigned)((tn >> 5) + 1);
            if (tid < 3) {
                unsigned it = 0;
                while (__hip_atomic_load(&prodflag[b * 3 + tid], __ATOMIC_RELAXED,
                                         __HIP_MEMORY_SCOPE_AGENT) < need) {
                    __builtin_amdgcn_s_sleep(8);
                    if (++it > (1u << 20)) break;
                }
            }
            __syncthreads();
            const int so = (tn & rmask) * 128;
            zr_c = __hip_atomic_load(zrb + so, __ATOMIC_RELAXED, __HIP_MEMORY_SCOPE_AGENT);
            hh_c = __hip_atomic_load(hhb + so, __ATOMIC_RELAXED, __HIP_MEMORY_SCOPE_AGENT);
        }
    }
}

extern "C" void kernel_launch(void* const* d_in, const int* in_sizes, int n_in,
                              void* d_out, int out_size, void* d_ws, size_t ws_size,
                              hipStream_t stream) {
    const float* x  = (const float*)d_in[0];
    const float* Wz = (const float*)d_in[1];
    const float* bz = (const float*)d_in[2];
    const float* Wr = (const float*)d_in[3];
    const float* br = (const float*)d_in[4];
    const float* Wh = (const float*)d_in[5];
    const float* bh = (const float*)d_in[6];
    float* outp = (float*)d_out;

    // ring sizing: per ring-step bytes = NB*128*12 = 96 KiB
    const size_t base = 4096;
    int ring = 32;
    for (int r = 2048; r >= 32; r >>= 1) {
        const size_t need = base + (size_t)NB * r * 128 * 12;
        if (need <= ws_size) { ring = r; break; }
    }
    char* w = (char*)d_ws;
    unsigned* prodflag = (unsigned*)w;                 // [64][3]
    unsigned* consflag = (unsigned*)(w + 1024);        // [64]
    unsigned long long* preZR = (unsigned long long*)(w + base);          // [64][ring][128]
    unsigned* preH = (unsigned*)(w + base + (size_t)NB * ring * 128 * 8); // [64][ring][128]

    hipMemsetAsync(w, 0, 4096, stream);  // flags must start at 0 each launch
    gru_fused<<<256, NTHR, 0, stream>>>(x, Wz, bz, Wr, br, Wh, bh, outp,
                                        prodflag, consflag, preZR, preH, ring);
}